// Round 8
// baseline (740.811 us; speedup 1.0000x reference)
//
#include <hip/hip_runtime.h>

#define B_   4096
#define T_   1024
#define IN_  5
#define H_   16
#define L_   4
#define OUT_ 150
#define NB   16     // batches per block (= MFMA M)
#define LDW  20     // LDS row stride in u32 (pad vs 16)

typedef int   v4i __attribute__((ext_vector_type(4)));
typedef float v4f __attribute__((ext_vector_type(4)));
typedef short v8h __attribute__((ext_vector_type(8)));

union Frag { v4i i; v8h h; };

__device__ __forceinline__ float fast_rcp(float x) { return __builtin_amdgcn_rcpf(x); }
__device__ __forceinline__ float sigm(float v) {
    float e = __expf(-v);
    return fast_rcp(1.0f + e);
}
__device__ __forceinline__ float tanh_fast(float v) {
    float e = __expf(-2.0f * fabsf(v));
    float t = (1.0f - e) * fast_rcp(1.0f + e);
    return copysignf(t, v);
}

// split v into bf16 hi (truncated) + exact residual lo; pack lo16=hi, hi16=lo
__device__ __forceinline__ unsigned packsplit(float v) {
    unsigned uh = __float_as_uint(v);
    float ah = __uint_as_float(uh & 0xFFFF0000u);
    float al = v - ah;                       // exact
    return (uh >> 16) | (__float_as_uint(al) & 0xFFFF0000u);
}

__device__ __forceinline__ v4f mfma16(v8h a, v8h b, v4f c) {
    return __builtin_amdgcn_mfma_f32_16x16x32_bf16(a, b, c, 0, 0, 0);
}

// LDS-only barrier: drain DS ops, do NOT drain vmcnt — in-flight global x
// prefetches survive the barrier (T4: never vmcnt(0) in the main loop).
__device__ __forceinline__ void barrier_lds() {
    asm volatile("s_waitcnt lgkmcnt(0)" ::: "memory");
    __builtin_amdgcn_s_barrier();
    asm volatile("" ::: "memory");
}

__global__ __launch_bounds__(256)
void gru_pipe(
    const float* __restrict__ x_in,
    const float* __restrict__ Wih0, const float* __restrict__ Whh0,
    const float* __restrict__ bih0, const float* __restrict__ bhh0,
    const float* __restrict__ Wih1, const float* __restrict__ Whh1,
    const float* __restrict__ bih1, const float* __restrict__ bhh1,
    const float* __restrict__ Wih2, const float* __restrict__ Whh2,
    const float* __restrict__ bih2, const float* __restrict__ bhh2,
    const float* __restrict__ Wih3, const float* __restrict__ Whh3,
    const float* __restrict__ bih3, const float* __restrict__ bhh3,
    const float* __restrict__ fcw,  const float* __restrict__ fcb,
    float* __restrict__ out)
{
    // h^l packed split-bf16, double-buffered by tick parity
    __shared__ int   hbuf[L_][2][NB * LDW];
    __shared__ float fchid[NB][L_ * H_];     // exact fp32 final h for FC

    const int tid  = threadIdx.x;
    const int w    = tid >> 6;               // wave index == layer index
    const int lane = tid & 63;
    const int q    = lane >> 4;              // k-block / batch-row-group selector
    const int mm   = lane & 15;              // A-row (batch) / D-col (j) index
    const int b0   = blockIdx.x * NB;

    // ---- this wave's weight pointers ----
    const float *wi, *wh, *bip, *bhp;
    if      (w == 0) { wi = Wih0; wh = Whh0; bip = bih0; bhp = bhh0; }
    else if (w == 1) { wi = Wih1; wh = Whh1; bip = bih1; bhp = bhh1; }
    else if (w == 2) { wi = Wih2; wh = Whh2; bip = bih2; bhp = bhh2; }
    else             { wi = Wih3; wh = Whh3; bip = bih3; bhp = bhh3; }
    const int KX = (w == 0) ? IN_ : H_;

    // ---- zero hbuf (both parities) ----
    for (int i = tid; i < L_ * 2 * NB * LDW; i += 256) (&hbuf[0][0][0])[i] = 0;

    // ---- B fragments for THIS layer (register-resident, split bf16) ----
    // B[k][n], K=32: k<16 = x side, k>=16 = h side. tiles: 0=r,1=z,2=n_x,3=n_h
    Frag Bh[4], Bl[4];
    float bias[4];
#pragma unroll
    for (int tile = 0; tile < 4; ++tile) {
        const int rowbase = (tile == 0) ? 0 : (tile == 1) ? 16 : 32;
        const int r = rowbase + mm;
        float vals[8];
#pragma unroll
        for (int e = 0; e < 8; ++e) {
            const int k = q * 8 + e;
            float v = 0.0f;
            if (k < 16) { if (tile != 3 && k < KX) v = wi[r * KX + k]; }
            else        { if (tile != 2)           v = wh[r * H_ + (k - 16)]; }
            vals[e] = v;
        }
#pragma unroll
        for (int d = 0; d < 4; ++d) {
            unsigned p0 = packsplit(vals[2 * d]);
            unsigned p1 = packsplit(vals[2 * d + 1]);
            Bh[tile].i[d] = (int)((p0 & 0xFFFFu) | (p1 << 16));
            Bl[tile].i[d] = (int)((p0 >> 16) | (p1 & 0xFFFF0000u));
        }
    }
    bias[0] = bip[mm]      + bhp[mm];
    bias[1] = bip[16 + mm] + bhp[16 + mm];
    bias[2] = bip[32 + mm];
    bias[3] = bhp[32 + mm];

    __syncthreads();   // prologue: full drain once is fine

    // ---- wave-0 x state: lane (q==0, mm) owns x[b0+mm][t][0..4] ----
    const float* xptr = x_in + (size_t)(b0 + mm) * T_ * IN_;
    float xA[5] = {0, 0, 0, 0, 0};    // even ticks (t = k)
    float xB[5] = {0, 0, 0, 0, 0};    // odd ticks
    if (w == 0 && q == 0) {
#pragma unroll
        for (int c = 0; c < IN_; ++c) xA[c] = xptr[c];            // t=0
#pragma unroll
        for (int c = 0; c < IN_; ++c) xB[c] = xptr[IN_ + c];      // t=1
    }

    float hold[4] = {0.0f, 0.0f, 0.0f, 0.0f};   // exact fp32 h, batch = q*4+reg

    // ---- one pipeline tick: wave w processes time t = k - w ----
    auto tick = [&](int k, float (&xv)[5]) {
        const int t = k - w;
        if (0 <= t && t < T_) {
            const int rp = (k - 1) & 1;      // parity holding inputs

            // ---- A fragment: rows = batch(mm), k-slot = q*8+e ----
            Frag Ah, Al;
            if (w == 0 && q < 2) {
                if (q == 0) {
                    unsigned p0 = packsplit(xv[0]), p1 = packsplit(xv[1]);
                    unsigned p2 = packsplit(xv[2]), p3 = packsplit(xv[3]);
                    unsigned p4 = packsplit(xv[4]);
                    Ah.i[0] = (int)((p0 & 0xFFFFu) | (p1 << 16));
                    Al.i[0] = (int)((p0 >> 16) | (p1 & 0xFFFF0000u));
                    Ah.i[1] = (int)((p2 & 0xFFFFu) | (p3 << 16));
                    Al.i[1] = (int)((p2 >> 16) | (p3 & 0xFFFF0000u));
                    Ah.i[2] = (int)(p4 & 0xFFFFu);
                    Al.i[2] = (int)(p4 >> 16);
                    Ah.i[3] = 0; Al.i[3] = 0;
                } else {
                    Ah.i[0] = Ah.i[1] = Ah.i[2] = Ah.i[3] = 0;
                    Al.i[0] = Al.i[1] = Al.i[2] = Al.i[3] = 0;
                }
            } else {
                const int up = (w > 0) ? (w - 1) : 0;
                const int* asrc = (q < 2) ? &hbuf[up][rp][0] : &hbuf[w][rp][0];
                const int ao = mm * LDW + (q & 1) * 8;
                int u0 = asrc[ao + 0], u1 = asrc[ao + 1], u2 = asrc[ao + 2], u3 = asrc[ao + 3];
                int u4 = asrc[ao + 4], u5 = asrc[ao + 5], u6 = asrc[ao + 6], u7 = asrc[ao + 7];
                Ah.i[0] = (int)__builtin_amdgcn_perm((unsigned)u1, (unsigned)u0, 0x05040100u);
                Ah.i[1] = (int)__builtin_amdgcn_perm((unsigned)u3, (unsigned)u2, 0x05040100u);
                Ah.i[2] = (int)__builtin_amdgcn_perm((unsigned)u5, (unsigned)u4, 0x05040100u);
                Ah.i[3] = (int)__builtin_amdgcn_perm((unsigned)u7, (unsigned)u6, 0x05040100u);
                Al.i[0] = (int)__builtin_amdgcn_perm((unsigned)u1, (unsigned)u0, 0x07060302u);
                Al.i[1] = (int)__builtin_amdgcn_perm((unsigned)u3, (unsigned)u2, 0x07060302u);
                Al.i[2] = (int)__builtin_amdgcn_perm((unsigned)u5, (unsigned)u4, 0x07060302u);
                Al.i[3] = (int)__builtin_amdgcn_perm((unsigned)u7, (unsigned)u6, 0x07060302u);
            }

            // issue x load for t+2 into the SAME set (consumed 2 ticks later;
            // barriers no longer drain vmcnt, so it stays in flight)
            if (w == 0 && q == 0) {
                const int tn = (t + 2 < T_) ? (t + 2) : (T_ - 1);
                const float* xp = xptr + tn * IN_;
#pragma unroll
                for (int c = 0; c < IN_; ++c) xv[c] = xp[c];
            }

            // ---- 12 independent MFMAs (no accumulate chain) ----
            v4f ahh[4], ahl[4], alh[4];
#pragma unroll
            for (int i = 0; i < 4; ++i) {
                v4f cb = {bias[i], bias[i], bias[i], bias[i]};
                v4f zz = {0.0f, 0.0f, 0.0f, 0.0f};
                ahh[i] = mfma16(Ah.h, Bh[i].h, cb);
                ahl[i] = mfma16(Ah.h, Bl[i].h, zz);
                alh[i] = mfma16(Al.h, Bh[i].h, zz);
            }

            // ---- gate tail: lane holds (batch=q*4+reg, j=mm) ----
            const int wp = k & 1;
#pragma unroll
            for (int reg = 0; reg < 4; ++reg) {
                float g0 = (ahh[0][reg] + ahl[0][reg]) + alh[0][reg];
                float g1 = (ahh[1][reg] + ahl[1][reg]) + alh[1][reg];
                float g2 = (ahh[2][reg] + ahl[2][reg]) + alh[2][reg];
                float g3 = (ahh[3][reg] + ahl[3][reg]) + alh[3][reg];
                float r = sigm(g0);
                float z = sigm(g1);
                float n = tanh_fast(fmaf(r, g3, g2));
                float h = fmaf(z, hold[reg] - n, n);
                hold[reg] = h;
                hbuf[w][wp][(q * 4 + reg) * LDW + mm] = (int)packsplit(h);
            }
        }
        barrier_lds();
    };

    const int NT = T_ + L_ - 1;   // 1027
#pragma unroll 1
    for (int k = 0; k + 1 < NT; k += 2) {
        tick(k, xA);
        tick(k + 1, xB);
    }
    tick(NT - 1, xA);   // leftover tick (k=1026, even)

    // ---- FC epilogue: exact fp32 hidden from hold regs ----
#pragma unroll
    for (int reg = 0; reg < 4; ++reg)
        fchid[q * 4 + reg][w * H_ + mm] = hold[reg];
    barrier_lds();

    for (int o = tid; o < NB * OUT_; o += 256) {
        const int m = o / OUT_, oc = o % OUT_;
        float acc = fcb[oc];
#pragma unroll
        for (int kk = 0; kk < L_ * H_; ++kk)
            acc = fmaf(fcw[oc * (L_ * H_) + kk], fchid[m][kk], acc);
        out[(size_t)(b0 + m) * OUT_ + oc] = acc;
    }
}

extern "C" void kernel_launch(void* const* d_in, const int* in_sizes, int n_in,
                              void* d_out, int out_size, void* d_ws, size_t ws_size,
                              hipStream_t stream) {
    const float* xin = (const float*)d_in[0];
    // d_in[1] = target_seq: unused by the reference output
    gru_pipe<<<B_ / NB, 256, 0, stream>>>(
        xin,
        (const float*)d_in[2],  (const float*)d_in[3],  (const float*)d_in[4],  (const float*)d_in[5],
        (const float*)d_in[6],  (const float*)d_in[7],  (const float*)d_in[8],  (const float*)d_in[9],
        (const float*)d_in[10], (const float*)d_in[11], (const float*)d_in[12], (const float*)d_in[13],
        (const float*)d_in[14], (const float*)d_in[15], (const float*)d_in[16], (const float*)d_in[17],
        (const float*)d_in[18], (const float*)d_in[19],
        (float*)d_out);
}

// Round 9
// 563.660 us; speedup vs baseline: 1.3143x; 1.3143x over previous
//
#include <hip/hip_runtime.h>

#define B_   4096
#define T_   1024
#define IN_  5
#define H_   16
#define L_   4
#define OUT_ 150
#define NB   16     // batches per block (= MFMA M)
#define LDW  20     // LDS row stride in u32 (pad vs 16)

typedef int   v4i __attribute__((ext_vector_type(4)));
typedef float v4f __attribute__((ext_vector_type(4)));
typedef short v8h __attribute__((ext_vector_type(8)));

union Frag { v4i i; v8h h; };

__device__ __forceinline__ float fast_rcp(float x) { return __builtin_amdgcn_rcpf(x); }
__device__ __forceinline__ float sigm(float v) {
    float e = __expf(-v);
    return fast_rcp(1.0f + e);
}
__device__ __forceinline__ float tanh_fast(float v) {
    float e = __expf(-2.0f * fabsf(v));
    float t = (1.0f - e) * fast_rcp(1.0f + e);
    return copysignf(t, v);
}

// split v into bf16 hi (truncated) + exact residual lo; pack lo16=hi, hi16=lo
__device__ __forceinline__ unsigned packsplit(float v) {
    unsigned uh = __float_as_uint(v);
    float ah = __uint_as_float(uh & 0xFFFF0000u);
    float al = v - ah;                       // exact
    return (uh >> 16) | (__float_as_uint(al) & 0xFFFF0000u);
}

__device__ __forceinline__ v4f mfma16(v8h a, v8h b, v4f c) {
    return __builtin_amdgcn_mfma_f32_16x16x32_bf16(a, b, c, 0, 0, 0);
}

// LDS-only barrier: drain DS ops, do NOT drain vmcnt — in-flight global x
// prefetches survive the barrier.
__device__ __forceinline__ void barrier_lds() {
    asm volatile("s_waitcnt lgkmcnt(0)" ::: "memory");
    __builtin_amdgcn_s_barrier();
    asm volatile("" ::: "memory");
}

__global__ __launch_bounds__(256)
void gru_pipe2(
    const float* __restrict__ x_in,
    const float* __restrict__ Wih0, const float* __restrict__ Whh0,
    const float* __restrict__ bih0, const float* __restrict__ bhh0,
    const float* __restrict__ Wih1, const float* __restrict__ Whh1,
    const float* __restrict__ bih1, const float* __restrict__ bhh1,
    const float* __restrict__ Wih2, const float* __restrict__ Whh2,
    const float* __restrict__ bih2, const float* __restrict__ bhh2,
    const float* __restrict__ Wih3, const float* __restrict__ Whh3,
    const float* __restrict__ bih3, const float* __restrict__ bhh3,
    const float* __restrict__ fcw,  const float* __restrict__ fcb,
    float* __restrict__ out)
{
    // h^l packed split-bf16: [layer][interval-parity][step 0/1][NB*LDW]
    __shared__ int   hbuf[L_][2][2][NB * LDW];
    __shared__ float fchid[NB][L_ * H_];

    const int tid  = threadIdx.x;
    const int w    = tid >> 6;               // wave index == layer index
    const int lane = tid & 63;
    const int q    = lane >> 4;
    const int mm   = lane & 15;              // A-row (batch) / D-col (j)
    const int b0   = blockIdx.x * NB;

    const float *wi, *wh, *bip, *bhp;
    if      (w == 0) { wi = Wih0; wh = Whh0; bip = bih0; bhp = bhh0; }
    else if (w == 1) { wi = Wih1; wh = Whh1; bip = bih1; bhp = bhh1; }
    else if (w == 2) { wi = Wih2; wh = Whh2; bip = bih2; bhp = bhh2; }
    else             { wi = Wih3; wh = Whh3; bip = bih3; bhp = bhh3; }
    const int KX = (w == 0) ? IN_ : H_;

    for (int i = tid; i < L_ * 2 * 2 * NB * LDW; i += 256) (&hbuf[0][0][0][0])[i] = 0;

    // ---- B fragments for THIS layer (register-resident, split bf16) ----
    Frag Bh[4], Bl[4];
    float bias[4];
#pragma unroll
    for (int tile = 0; tile < 4; ++tile) {
        const int rowbase = (tile == 0) ? 0 : (tile == 1) ? 16 : 32;
        const int r = rowbase + mm;
        float vals[8];
#pragma unroll
        for (int e = 0; e < 8; ++e) {
            const int k = q * 8 + e;
            float v = 0.0f;
            if (k < 16) { if (tile != 3 && k < KX) v = wi[r * KX + k]; }
            else        { if (tile != 2)           v = wh[r * H_ + (k - 16)]; }
            vals[e] = v;
        }
#pragma unroll
        for (int d = 0; d < 4; ++d) {
            unsigned p0 = packsplit(vals[2 * d]);
            unsigned p1 = packsplit(vals[2 * d + 1]);
            Bh[tile].i[d] = (int)((p0 & 0xFFFFu) | (p1 << 16));
            Bl[tile].i[d] = (int)((p0 >> 16) | (p1 & 0xFFFF0000u));
        }
    }
    bias[0] = bip[mm]      + bhp[mm];
    bias[1] = bip[16 + mm] + bhp[16 + mm];
    bias[2] = bip[32 + mm];
    bias[3] = bhp[32 + mm];

    __syncthreads();

    // ---- x state: wave0/q==0 lane mm owns x[b0+mm][t][0..4]; 2 steps/set ----
    const float* xptr = x_in + (size_t)(b0 + mm) * T_ * IN_;
    float xA[10], xB[10];
#pragma unroll
    for (int c = 0; c < 10; ++c) { xA[c] = 0.0f; xB[c] = 0.0f; }
    if (w == 0 && q == 0) {
#pragma unroll
        for (int c = 0; c < 10; ++c) xA[c] = xptr[c];          // t = 0,1
#pragma unroll
        for (int c = 0; c < 10; ++c) xB[c] = xptr[10 + c];     // t = 2,3
    }

    float hold[4] = {0.0f, 0.0f, 0.0f, 0.0f};

    // build a K=16 x-side fragment pair from 5 scalars (zeros for q!=0 lanes)
#define XFRAG(FH, FL, X0, X1, X2, X3, X4)                                  \
    {                                                                      \
        unsigned p0 = packsplit(X0), p1 = packsplit(X1);                   \
        unsigned p2 = packsplit(X2), p3 = packsplit(X3);                   \
        unsigned p4 = packsplit(X4);                                       \
        FH.i[0] = (int)((p0 & 0xFFFFu) | (p1 << 16));                      \
        FL.i[0] = (int)((p0 >> 16) | (p1 & 0xFFFF0000u));                  \
        FH.i[1] = (int)((p2 & 0xFFFFu) | (p3 << 16));                      \
        FL.i[1] = (int)((p2 >> 16) | (p3 & 0xFFFF0000u));                  \
        FH.i[2] = (int)(p4 & 0xFFFFu);                                     \
        FL.i[2] = (int)(p4 >> 16);                                         \
        FH.i[3] = 0; FL.i[3] = 0;                                          \
    }

    // one GRU step: A from {x-frag | upstream LDS | self LDS}, chained MFMA,
    // gate tail, h write to DST
#define DO_STEP(UPS, SELF, DST, XFH, XFL)                                  \
    {                                                                      \
        Frag Ah, Al;                                                       \
        if (w == 0 && q < 2) {                                             \
            Ah = (XFH); Al = (XFL);                                        \
        } else {                                                           \
            const int* asrc = (q < 2) ? (UPS) : (SELF);                    \
            const int ao = mm * LDW + (q & 1) * 8;                         \
            int u0 = asrc[ao + 0], u1 = asrc[ao + 1], u2 = asrc[ao + 2], u3 = asrc[ao + 3]; \
            int u4 = asrc[ao + 4], u5 = asrc[ao + 5], u6 = asrc[ao + 6], u7 = asrc[ao + 7]; \
            Ah.i[0] = (int)__builtin_amdgcn_perm((unsigned)u1, (unsigned)u0, 0x05040100u);  \
            Ah.i[1] = (int)__builtin_amdgcn_perm((unsigned)u3, (unsigned)u2, 0x05040100u);  \
            Ah.i[2] = (int)__builtin_amdgcn_perm((unsigned)u5, (unsigned)u4, 0x05040100u);  \
            Ah.i[3] = (int)__builtin_amdgcn_perm((unsigned)u7, (unsigned)u6, 0x05040100u);  \
            Al.i[0] = (int)__builtin_amdgcn_perm((unsigned)u1, (unsigned)u0, 0x07060302u);  \
            Al.i[1] = (int)__builtin_amdgcn_perm((unsigned)u3, (unsigned)u2, 0x07060302u);  \
            Al.i[2] = (int)__builtin_amdgcn_perm((unsigned)u5, (unsigned)u4, 0x07060302u);  \
            Al.i[3] = (int)__builtin_amdgcn_perm((unsigned)u7, (unsigned)u6, 0x07060302u);  \
        }                                                                  \
        v4f a0 = {bias[0], bias[0], bias[0], bias[0]};                     \
        v4f a1 = {bias[1], bias[1], bias[1], bias[1]};                     \
        v4f a2 = {bias[2], bias[2], bias[2], bias[2]};                     \
        v4f a3 = {bias[3], bias[3], bias[3], bias[3]};                     \
        a0 = mfma16(Al.h, Bh[0].h, a0);                                    \
        a1 = mfma16(Al.h, Bh[1].h, a1);                                    \
        a2 = mfma16(Al.h, Bh[2].h, a2);                                    \
        a3 = mfma16(Al.h, Bh[3].h, a3);                                    \
        a0 = mfma16(Ah.h, Bl[0].h, a0);                                    \
        a1 = mfma16(Ah.h, Bl[1].h, a1);                                    \
        a2 = mfma16(Ah.h, Bl[2].h, a2);                                    \
        a3 = mfma16(Ah.h, Bl[3].h, a3);                                    \
        a0 = mfma16(Ah.h, Bh[0].h, a0);                                    \
        a1 = mfma16(Ah.h, Bh[1].h, a1);                                    \
        a2 = mfma16(Ah.h, Bh[2].h, a2);                                    \
        a3 = mfma16(Ah.h, Bh[3].h, a3);                                    \
        _Pragma("unroll")                                                  \
        for (int reg = 0; reg < 4; ++reg) {                                \
            float r = sigm(a0[reg]);                                       \
            float z = sigm(a1[reg]);                                       \
            float n = tanh_fast(fmaf(r, a3[reg], a2[reg]));                \
            float h = fmaf(z, hold[reg] - n, n);                           \
            hold[reg] = h;                                                 \
            (DST)[(q * 4 + reg) * LDW + mm] = (int)packsplit(h);           \
        }                                                                  \
    }

    // one barrier interval = 2 GRU steps (t0 = 2*(k-w), t1 = t0+1)
#define INTERVAL(K, RP, WP, XV)                                            \
    {                                                                      \
        const int t0 = 2 * ((K) - w);                                      \
        if (0 <= t0 && t0 < T_ - 1) {                                      \
            Frag xf0h, xf0l, xf1h, xf1l;                                   \
            if (w == 0) {                                                  \
                XFRAG(xf0h, xf0l, XV[0], XV[1], XV[2], XV[3], XV[4])       \
                XFRAG(xf1h, xf1l, XV[5], XV[6], XV[7], XV[8], XV[9])       \
                if (q == 0) {   /* prefetch x for interval K+2 */          \
                    const int c0 = (t0 + 4 < T_) ? (t0 + 4) : (T_ - 2);    \
                    const float* xp = xptr + c0 * IN_;                     \
                    _Pragma("unroll")                                      \
                    for (int c = 0; c < 10; ++c) XV[c] = xp[c];            \
                }                                                          \
            }                                                              \
            const int up = (w > 0) ? (w - 1) : 0;                          \
            DO_STEP(&hbuf[up][RP][0][0], &hbuf[w][RP][1][0],               \
                    &hbuf[w][WP][0][0], xf0h, xf0l)                        \
            asm volatile("" ::: "memory");                                 \
            DO_STEP(&hbuf[up][RP][1][0], &hbuf[w][WP][0][0],               \
                    &hbuf[w][WP][1][0], xf1h, xf1l)                        \
        }                                                                  \
        barrier_lds();                                                     \
    }

    const int NI = T_ / 2 + L_ - 1;   // 515 intervals
#pragma unroll 1
    for (int k = 0; k + 1 < NI; k += 2) {
        INTERVAL(k,     1, 0, xA)
        INTERVAL(k + 1, 0, 1, xB)
    }
    INTERVAL(NI - 1, 1, 0, xA)        // k = 514 (even)

#undef INTERVAL
#undef DO_STEP
#undef XFRAG

    // ---- FC epilogue: exact fp32 hidden from hold regs ----
#pragma unroll
    for (int reg = 0; reg < 4; ++reg)
        fchid[q * 4 + reg][w * H_ + mm] = hold[reg];
    barrier_lds();

    for (int o = tid; o < NB * OUT_; o += 256) {
        const int m = o / OUT_, oc = o % OUT_;
        float acc = fcb[oc];
#pragma unroll
        for (int kk = 0; kk < L_ * H_; ++kk)
            acc = fmaf(fcw[oc * (L_ * H_) + kk], fchid[m][kk], acc);
        out[(size_t)(b0 + m) * OUT_ + oc] = acc;
    }
}

extern "C" void kernel_launch(void* const* d_in, const int* in_sizes, int n_in,
                              void* d_out, int out_size, void* d_ws, size_t ws_size,
                              hipStream_t stream) {
    const float* xin = (const float*)d_in[0];
    // d_in[1] = target_seq: unused by the reference output
    gru_pipe2<<<B_ / NB, 256, 0, stream>>>(
        xin,
        (const float*)d_in[2],  (const float*)d_in[3],  (const float*)d_in[4],  (const float*)d_in[5],
        (const float*)d_in[6],  (const float*)d_in[7],  (const float*)d_in[8],  (const float*)d_in[9],
        (const float*)d_in[10], (const float*)d_in[11], (const float*)d_in[12], (const float*)d_in[13],
        (const float*)d_in[14], (const float*)d_in[15], (const float*)d_in[16], (const float*)d_in[17],
        (const float*)d_in[18], (const float*)d_in[19],
        (float*)d_out);
}

// Round 11
// 439.301 us; speedup vs baseline: 1.6863x; 1.2831x over previous
//
#include <hip/hip_runtime.h>

#define B_   4096
#define T_   1024
#define IN_  5
#define H_   16
#define L_   4
#define OUT_ 150
#define NB   16     // batches per block (= MFMA M)
#define LDW  12     // ints per batch-row in LDS (8 f16-pairs data + 4 pad; 48B -> b128-aligned)
#define SPI  4      // GRU steps per barrier interval

typedef int      v4i  __attribute__((ext_vector_type(4)));
typedef float    v4f  __attribute__((ext_vector_type(4)));
typedef float    f4   __attribute__((ext_vector_type(4)));
typedef _Float16 v8h  __attribute__((ext_vector_type(8)));

typedef v4i v4i_ma __attribute__((may_alias));
typedef f4  f4_ma  __attribute__((may_alias));
typedef unsigned short u16_ma __attribute__((may_alias));

union Frag { v4i i; v8h h; };

__device__ __forceinline__ float fast_rcp(float x) { return __builtin_amdgcn_rcpf(x); }
__device__ __forceinline__ float sigm(float v) {
    float e = __expf(-v);
    return fast_rcp(1.0f + e);
}
__device__ __forceinline__ float tanh_fast(float v) {
    float e = __expf(-2.0f * fabsf(v));
    float t = (1.0f - e) * fast_rcp(1.0f + e);
    return copysignf(t, v);
}

__device__ __forceinline__ int pk(float a, float b) {
    return __builtin_bit_cast(int, __builtin_amdgcn_cvt_pkrtz(a, b));
}

__device__ __forceinline__ v4f mfma16h(v8h a, v8h b, v4f c) {
    return __builtin_amdgcn_mfma_f32_16x16x32_f16(a, b, c, 0, 0, 0);
}

// LDS-only barrier: drain DS ops, keep global loads in flight (no vmcnt drain)
__device__ __forceinline__ void barrier_lds() {
    asm volatile("s_waitcnt lgkmcnt(0)" ::: "memory");
    __builtin_amdgcn_s_barrier();
    asm volatile("" ::: "memory");
}

__global__ __launch_bounds__(256)
void gru_f16(
    const float* __restrict__ x_in,
    const float* __restrict__ Wih0, const float* __restrict__ Whh0,
    const float* __restrict__ bih0, const float* __restrict__ bhh0,
    const float* __restrict__ Wih1, const float* __restrict__ Whh1,
    const float* __restrict__ bih1, const float* __restrict__ bhh1,
    const float* __restrict__ Wih2, const float* __restrict__ Whh2,
    const float* __restrict__ bih2, const float* __restrict__ bhh2,
    const float* __restrict__ Wih3, const float* __restrict__ Whh3,
    const float* __restrict__ bih3, const float* __restrict__ bhh3,
    const float* __restrict__ fcw,  const float* __restrict__ fcb,
    float* __restrict__ out)
{
    // h^l as f16 pairs: [layer][interval-parity][step][batch*LDW ints]
    __shared__ int   hbuf[L_][2][SPI][NB * LDW];
    __shared__ float fchid[NB][L_ * H_];

    const int tid  = threadIdx.x;
    const int w    = tid >> 6;               // wave index == layer index
    const int lane = tid & 63;
    const int q    = lane >> 4;              // k-block / batch-row-group selector
    const int mm   = lane & 15;              // A-row (batch) / D-col (j)
    const int b0   = blockIdx.x * NB;

    const float *wi, *wh, *bip, *bhp;
    if      (w == 0) { wi = Wih0; wh = Whh0; bip = bih0; bhp = bhh0; }
    else if (w == 1) { wi = Wih1; wh = Whh1; bip = bih1; bhp = bhh1; }
    else if (w == 2) { wi = Wih2; wh = Whh2; bip = bih2; bhp = bhh2; }
    else             { wi = Wih3; wh = Whh3; bip = bih3; bhp = bhh3; }
    const int KX = (w == 0) ? IN_ : H_;

    for (int i = tid; i < L_ * 2 * SPI * NB * LDW; i += 256) (&hbuf[0][0][0][0])[i] = 0;

    // ---- B fragments, single f16 (register-resident) ----
    // B[k][n], K=32: k<16 x-side, k>=16 h-side. tiles: 0=r,1=z,2=n_x,3=n_h
    Frag Bf[4];
    v4f  cb[4];      // bias as MFMA C-operand (no per-step splat)
    {
        float bias[4];
        bias[0] = bip[mm]      + bhp[mm];
        bias[1] = bip[16 + mm] + bhp[16 + mm];
        bias[2] = bip[32 + mm];
        bias[3] = bhp[32 + mm];
#pragma unroll
        for (int tile = 0; tile < 4; ++tile) {
            const int rowbase = (tile == 0) ? 0 : (tile == 1) ? 16 : 32;
            const int r = rowbase + mm;
            float vals[8];
#pragma unroll
            for (int e = 0; e < 8; ++e) {
                const int k = q * 8 + e;
                float v = 0.0f;
                if (k < 16) { if (tile != 3 && k < KX) v = wi[r * KX + k]; }
                else        { if (tile != 2)           v = wh[r * H_ + (k - 16)]; }
                vals[e] = v;
            }
#pragma unroll
            for (int d = 0; d < 4; ++d)
                Bf[tile].i[d] = pk(vals[2 * d], vals[2 * d + 1]);
            cb[tile] = (v4f){bias[tile], bias[tile], bias[tile], bias[tile]};
        }
    }

    __syncthreads();

    // ---- x state: wave0/q==0 lane mm owns x[b0+mm][t][0..4], SPI steps/buffer ----
    const float* xptr = x_in + (size_t)(b0 + mm) * T_ * IN_;
    float XV[5 * SPI];
#pragma unroll
    for (int c = 0; c < 5 * SPI; ++c) XV[c] = 0.0f;
    if (w == 0 && q == 0) {
#pragma unroll
        for (int c = 0; c < 5; ++c)   // 20 consecutive floats, 16B-aligned
            ((f4*)XV)[c] = *(const f4_ma*)(xptr + 4 * c);
    }

    float hold[4] = {0.0f, 0.0f, 0.0f, 0.0f};   // exact fp32 h, batch = q*4+reg

    const int up = (w > 0) ? (w - 1) : 0;
    const int NI = T_ / SPI + L_ - 1;            // 259

#pragma unroll 1
    for (int k = 0; k < NI; ++k) {
        const int wp = k & 1, rp = wp ^ 1;
        const int t0 = SPI * (k - w);
        if (0 <= t0 && t0 < T_) {
            // x fragments for this interval (meaningful on wave 0 only)
            int xf[SPI][3];
            if (w == 0) {
#pragma unroll
                for (int s = 0; s < SPI; ++s) {
                    xf[s][0] = pk(XV[5 * s + 0], XV[5 * s + 1]);
                    xf[s][1] = pk(XV[5 * s + 2], XV[5 * s + 3]);
                    xf[s][2] = pk(XV[5 * s + 4], 0.0f);
                }
                if (q == 0) {   // prefetch next interval's x (consumed next interval)
                    const int c0 = (t0 + SPI <= T_ - SPI) ? (t0 + SPI) : (T_ - SPI);
                    const float* xp = xptr + c0 * IN_;
#pragma unroll
                    for (int c = 0; c < 5; ++c)
                        ((f4*)XV)[c] = *(const f4_ma*)(xp + 4 * c);
                }
            }

#pragma unroll
            for (int s = 0; s < SPI; ++s) {
                // ---- A fragment: one b128 read; layout == fragment layout ----
                const int* upsrc = &hbuf[up][rp][s][0];
                const int* self  = (s == 0) ? &hbuf[w][rp][SPI - 1][0]
                                            : &hbuf[w][wp][s - 1][0];
                const int* asrc  = (q < 2) ? upsrc : self;
                Frag A;
                A.i = *(const v4i_ma*)&asrc[mm * LDW + (q & 1) * 4];
                if (w == 0) {   // q<2 lanes use x regs (q==1 lanes all zero)
                    const bool usex = (q < 2);
                    A.i[0] = usex ? ((q == 0) ? xf[s][0] : 0) : A.i[0];
                    A.i[1] = usex ? ((q == 0) ? xf[s][1] : 0) : A.i[1];
                    A.i[2] = usex ? ((q == 0) ? xf[s][2] : 0) : A.i[2];
                    A.i[3] = usex ? 0 : A.i[3];
                }

                // ---- 4 MFMAs, one per gate tile, bias in C ----
                v4f a0 = mfma16h(A.h, Bf[0].h, cb[0]);
                v4f a1 = mfma16h(A.h, Bf[1].h, cb[1]);
                v4f a2 = mfma16h(A.h, Bf[2].h, cb[2]);
                v4f a3 = mfma16h(A.h, Bf[3].h, cb[3]);

                // ---- gate tail: lane holds (batch=q*4+reg, j=mm) ----
                u16_ma* dsth = (u16_ma*)&hbuf[w][wp][s][0];
#pragma unroll
                for (int reg = 0; reg < 4; ++reg) {
                    float r = sigm(a0[reg]);
                    float z = sigm(a1[reg]);
                    float n = tanh_fast(fmaf(r, a3[reg], a2[reg]));
                    float h = fmaf(z, hold[reg] - n, n);
                    hold[reg] = h;
                    dsth[(q * 4 + reg) * (LDW * 2) + mm] =
                        __builtin_bit_cast(unsigned short, (_Float16)h);
                }
                asm volatile("" ::: "memory");   // order writes vs next step's reads
            }
        }
        barrier_lds();
    }

    // ---- FC epilogue: exact fp32 hidden from hold regs ----
#pragma unroll
    for (int reg = 0; reg < 4; ++reg)
        fchid[q * 4 + reg][w * H_ + mm] = hold[reg];
    barrier_lds();

    for (int o = tid; o < NB * OUT_; o += 256) {
        const int m = o / OUT_, oc = o % OUT_;
        float acc = fcb[oc];
#pragma unroll
        for (int kk = 0; kk < L_ * H_; ++kk)
            acc = fmaf(fcw[oc * (L_ * H_) + kk], fchid[m][kk], acc);
        out[(size_t)(b0 + m) * OUT_ + oc] = acc;
    }
}

extern "C" void kernel_launch(void* const* d_in, const int* in_sizes, int n_in,
                              void* d_out, int out_size, void* d_ws, size_t ws_size,
                              hipStream_t stream) {
    const float* xin = (const float*)d_in[0];
    // d_in[1] = target_seq: unused by the reference output
    gru_f16<<<B_ / NB, 256, 0, stream>>>(
        xin,
        (const float*)d_in[2],  (const float*)d_in[3],  (const float*)d_in[4],  (const float*)d_in[5],
        (const float*)d_in[6],  (const float*)d_in[7],  (const float*)d_in[8],  (const float*)d_in[9],
        (const float*)d_in[10], (const float*)d_in[11], (const float*)d_in[12], (const float*)d_in[13],
        (const float*)d_in[14], (const float*)d_in[15], (const float*)d_in[16], (const float*)d_in[17],
        (const float*)d_in[18], (const float*)d_in[19],
        (float*)d_out);
}

// Round 12
// 405.984 us; speedup vs baseline: 1.8247x; 1.0821x over previous
//
#include <hip/hip_runtime.h>

#define B_   4096
#define T_   1024
#define IN_  5
#define H_   16
#define L_   4
#define OUT_ 150
#define NB   16     // batches per block (= MFMA N now)
#define LDW  12     // ints per batch-row in LDS (8 used + 4 pad; 48B stride)
#define SPI  8      // GRU steps per barrier interval

typedef int      v4i  __attribute__((ext_vector_type(4)));
typedef int      v2i  __attribute__((ext_vector_type(2)));
typedef float    v4f  __attribute__((ext_vector_type(4)));
typedef float    f4   __attribute__((ext_vector_type(4)));
typedef _Float16 v8h  __attribute__((ext_vector_type(8)));

typedef v4i v4i_ma __attribute__((may_alias));
typedef v2i v2i_ma __attribute__((may_alias));
typedef f4  f4_ma  __attribute__((may_alias));

union Frag { v4i i; v8h h; };

__device__ __forceinline__ float fast_rcp(float x) { return __builtin_amdgcn_rcpf(x); }
__device__ __forceinline__ float sigm(float v) {
    float e = __expf(-v);
    return fast_rcp(1.0f + e);
}
__device__ __forceinline__ float tanh_fast(float v) {
    float e = __expf(-2.0f * fabsf(v));
    float t = (1.0f - e) * fast_rcp(1.0f + e);
    return copysignf(t, v);
}
__device__ __forceinline__ int pk(float a, float b) {
    return __builtin_bit_cast(int, __builtin_amdgcn_cvt_pkrtz(a, b));
}
__device__ __forceinline__ v4f mfma16h(v8h a, v8h b, v4f c) {
    return __builtin_amdgcn_mfma_f32_16x16x32_f16(a, b, c, 0, 0, 0);
}
// LDS-only barrier: drain DS, keep global x loads in flight (no vmcnt drain)
__device__ __forceinline__ void barrier_lds() {
    asm volatile("s_waitcnt lgkmcnt(0)" ::: "memory");
    __builtin_amdgcn_s_barrier();
    asm volatile("" ::: "memory");
}

__global__ __launch_bounds__(256)
__attribute__((amdgpu_waves_per_eu(1, 1)))
void gru_tr(
    const float* __restrict__ x_in,
    const float* __restrict__ Wih0, const float* __restrict__ Whh0,
    const float* __restrict__ bih0, const float* __restrict__ bhh0,
    const float* __restrict__ Wih1, const float* __restrict__ Whh1,
    const float* __restrict__ bih1, const float* __restrict__ bhh1,
    const float* __restrict__ Wih2, const float* __restrict__ Whh2,
    const float* __restrict__ bih2, const float* __restrict__ bhh2,
    const float* __restrict__ Wih3, const float* __restrict__ Whh3,
    const float* __restrict__ bih3, const float* __restrict__ bhh3,
    const float* __restrict__ fcw,  const float* __restrict__ fcb,
    float* __restrict__ out)
{
    // cross-LAYER handoff only (self-h never touches LDS):
    // hbuf[layer 0..2][parity][step][batch*LDW ints]; int p holds h[j=2p..2p+1] f16
    __shared__ int   hbuf[L_ - 1][2][SPI][NB * LDW];
    __shared__ float fchid[NB][L_ * H_];

    const int tid  = threadIdx.x;
    const int w    = tid >> 6;               // wave index == layer index
    const int lane = tid & 63;
    const int q    = lane >> 4;              // k/row-group selector
    const int mm   = lane & 15;              // B-col = batch; A-row = gate n
    const int b0   = blockIdx.x * NB;

    const float *wi, *wh, *bip, *bhp;
    if      (w == 0) { wi = Wih0; wh = Whh0; bip = bih0; bhp = bhh0; }
    else if (w == 1) { wi = Wih1; wh = Whh1; bip = bih1; bhp = bhh1; }
    else if (w == 2) { wi = Wih2; wh = Whh2; bip = bih2; bhp = bhh2; }
    else             { wi = Wih3; wh = Whh3; bip = bih3; bhp = bhh3; }
    const int KX = (w == 0) ? IN_ : H_;

    for (int i = tid; i < (L_ - 1) * 2 * SPI * NB * LDW; i += 256)
        (&hbuf[0][0][0][0])[i] = 0;

    // ---- STATIC A fragments (weights): A_t[n=mm within tile][k=q*8+e] ----
    // K=32: k<16 x-side, k>=16 h-side. tiles: 0=r,1=z,2=n_x,3=n_h
    Frag Af[4];
    v4f  cb[4];      // bias as MFMA C; per-lane per-reg: n = q*4+reg
    {
#pragma unroll
        for (int tile = 0; tile < 4; ++tile) {
            const int rowbase = (tile == 0) ? 0 : (tile == 1) ? 16 : 32;
            const int r = rowbase + mm;
            float vals[8];
#pragma unroll
            for (int e = 0; e < 8; ++e) {
                const int k = q * 8 + e;
                float v = 0.0f;
                if (k < 16) { if (tile != 3 && k < KX) v = wi[r * KX + k]; }
                else        { if (tile != 2)           v = wh[r * H_ + (k - 16)]; }
                vals[e] = v;
            }
#pragma unroll
            for (int d = 0; d < 4; ++d)
                Af[tile].i[d] = pk(vals[2 * d], vals[2 * d + 1]);
#pragma unroll
            for (int reg = 0; reg < 4; ++reg) {
                const int n = q * 4 + reg;
                float b;
                if      (tile == 0) b = bip[n] + bhp[n];
                else if (tile == 1) b = bip[16 + n] + bhp[16 + n];
                else if (tile == 2) b = bip[32 + n];
                else                b = bhp[32 + n];
                cb[tile][reg] = b;
            }
        }
    }
    __syncthreads();

    // ---- x: wave0/q==0 lane mm owns batch b0+mm; interval-granular f4 loads ----
    const float* xptr = x_in + (size_t)(b0 + mm) * T_ * IN_;
    float XA[5 * SPI], XB[5 * SPI];
#pragma unroll
    for (int c = 0; c < 5 * SPI; ++c) { XA[c] = 0.0f; XB[c] = 0.0f; }
    if (w == 0 && q == 0) {
#pragma unroll
        for (int c = 0; c < 10; ++c)     // t0=0: 40 floats, 16B-aligned
            ((f4*)XA)[c] = *(const f4_ma*)(xptr + 4 * c);
    }

    float hold[4] = {0.0f, 0.0f, 0.0f, 0.0f};   // exact fp32 h[batch=mm][j=q*4+reg]
    int pkA = 0, pkB = 0;                        // f16 pairs (j=q*4..+1, q*4+2..+3)

    // fixed shfl source lanes for the self exchange (valid lanes even when unused)
    const int qq  = (q >= 2) ? (q - 2) : 0;
    const int s0l = (qq * 2) * 16 + mm;
    const int s1l = (qq * 2 + 1) * 16 + mm;

    const int NI = T_ / SPI + L_ - 1;            // 131

    auto body = [&](int k, float (&Xc)[5 * SPI], float (&Xn)[5 * SPI]) {
        const int t0 = SPI * (k - w);
        if (0 <= t0 && t0 < T_) {
            const int rp = (k - 1) & 1, wp = k & 1;

            // upstream fragments for all SPI steps (available since last barrier)
            Frag up[SPI];
            if (w > 0) {
#pragma unroll
                for (int s = 0; s < SPI; ++s)
                    up[s].i = *(const v4i_ma*)&hbuf[w - 1][rp][s][mm * LDW + (q & 1) * 4];
            }
            // prefetch next interval's x (in flight across the barrier)
            if (w == 0 && q == 0) {
                int tn0 = t0 + SPI; if (tn0 > T_ - SPI) tn0 = T_ - SPI;
                const float* xp = xptr + tn0 * IN_;
#pragma unroll
                for (int c = 0; c < 10; ++c)
                    ((f4*)Xn)[c] = *(const f4_ma*)(xp + 4 * c);
            }

#pragma unroll
            for (int s = 0; s < SPI; ++s) {
                // ---- self-h exchange: pure in-register (4 bpermutes) ----
                int sh0 = __shfl(pkA, s0l, 64);
                int sh1 = __shfl(pkB, s0l, 64);
                int sh2 = __shfl(pkA, s1l, 64);
                int sh3 = __shfl(pkB, s1l, 64);

                Frag Bf;   // B[k=q*8+e][col=batch mm]
                if (w == 0) {
                    int x0 = pk(Xc[5 * s + 0], Xc[5 * s + 1]);
                    int x1 = pk(Xc[5 * s + 2], Xc[5 * s + 3]);
                    int x2 = pk(Xc[5 * s + 4], 0.0f);
                    Bf.i[0] = (q >= 2) ? sh0 : ((q == 0) ? x0 : 0);
                    Bf.i[1] = (q >= 2) ? sh1 : ((q == 0) ? x1 : 0);
                    Bf.i[2] = (q >= 2) ? sh2 : ((q == 0) ? x2 : 0);
                    Bf.i[3] = (q >= 2) ? sh3 : 0;
                } else {
                    Bf.i[0] = (q >= 2) ? sh0 : up[s].i[0];
                    Bf.i[1] = (q >= 2) ? sh1 : up[s].i[1];
                    Bf.i[2] = (q >= 2) ? sh2 : up[s].i[2];
                    Bf.i[3] = (q >= 2) ? sh3 : up[s].i[3];
                }

                // ---- 4 MFMAs: G^T[n][batch], A static, bias in C ----
                v4f a0 = mfma16h(Af[0].h, Bf.h, cb[0]);
                v4f a1 = mfma16h(Af[1].h, Bf.h, cb[1]);
                v4f a2 = mfma16h(Af[2].h, Bf.h, cb[2]);
                v4f a3 = mfma16h(Af[3].h, Bf.h, cb[3]);

                // ---- tail: lane owns batch=mm, j=q*4+reg for all 4 gates ----
#pragma unroll
                for (int reg = 0; reg < 4; ++reg) {
                    float r = sigm(a0[reg]);
                    float z = sigm(a1[reg]);
                    float n = tanh_fast(fmaf(r, a3[reg], a2[reg]));
                    float h = fmaf(z, hold[reg] - n, n);
                    hold[reg] = h;
                }
                pkA = pk(hold[0], hold[1]);
                pkB = pk(hold[2], hold[3]);

                // ---- downstream handoff (layers 0..2): one b64 write ----
                if (w < 3)
                    *(v2i_ma*)&hbuf[w][wp][s][mm * LDW + q * 2] = (v2i){pkA, pkB};
            }
        }
        barrier_lds();
    };

#pragma unroll 1
    for (int k = 0; k + 1 < NI; k += 2) {
        body(k, XA, XB);
        body(k + 1, XB, XA);
    }
    body(NI - 1, XA, XB);   // k = 130 (even)

    // ---- FC epilogue: exact fp32 hidden from hold regs ----
#pragma unroll
    for (int reg = 0; reg < 4; ++reg)
        fchid[mm][w * H_ + q * 4 + reg] = hold[reg];
    barrier_lds();

    for (int o = tid; o < NB * OUT_; o += 256) {
        const int m = o / OUT_, oc = o % OUT_;
        float acc = fcb[oc];
#pragma unroll
        for (int kk = 0; kk < L_ * H_; ++kk)
            acc = fmaf(fcw[oc * (L_ * H_) + kk], fchid[m][kk], acc);
        out[(size_t)(b0 + m) * OUT_ + oc] = acc;
    }
}

extern "C" void kernel_launch(void* const* d_in, const int* in_sizes, int n_in,
                              void* d_out, int out_size, void* d_ws, size_t ws_size,
                              hipStream_t stream) {
    const float* xin = (const float*)d_in[0];
    // d_in[1] = target_seq: unused by the reference output
    gru_tr<<<B_ / NB, 256, 0, stream>>>(
        xin,
        (const float*)d_in[2],  (const float*)d_in[3],  (const float*)d_in[4],  (const float*)d_in[5],
        (const float*)d_in[6],  (const float*)d_in[7],  (const float*)d_in[8],  (const float*)d_in[9],
        (const float*)d_in[10], (const float*)d_in[11], (const float*)d_in[12], (const float*)d_in[13],
        (const float*)d_in[14], (const float*)d_in[15], (const float*)d_in[16], (const float*)d_in[17],
        (const float*)d_in[18], (const float*)d_in[19],
        (float*)d_out);
}

// Round 14
// 353.012 us; speedup vs baseline: 2.0985x; 1.1501x over previous
//
#include <hip/hip_runtime.h>

#define B_   4096
#define T_   1024
#define IN_  5
#define H_   16
#define L_   4
#define OUT_ 150
#define NB   16     // batches per block (= MFMA N)
#define LDW  12     // ints per batch-row in LDS (8 used + 4 pad; 48B stride)
#define SPI  8      // GRU steps per barrier interval

typedef int      v4i  __attribute__((ext_vector_type(4)));
typedef int      v2i  __attribute__((ext_vector_type(2)));
typedef float    v4f  __attribute__((ext_vector_type(4)));
typedef float    f4   __attribute__((ext_vector_type(4)));
typedef _Float16 v8h  __attribute__((ext_vector_type(8)));

typedef v4i v4i_ma __attribute__((may_alias));
typedef v2i v2i_ma __attribute__((may_alias));
typedef f4  f4_ma  __attribute__((may_alias));

union Frag { v4i i; v8h h; };

__device__ __forceinline__ float fast_rcp(float x) { return __builtin_amdgcn_rcpf(x); }
__device__ __forceinline__ float ex2(float x) {
#if __has_builtin(__builtin_amdgcn_exp2f)
    return __builtin_amdgcn_exp2f(x);
#else
    return exp2f(x);
#endif
}
__device__ __forceinline__ int pk(float a, float b) {
    return __builtin_bit_cast(int, __builtin_amdgcn_cvt_pkrtz(a, b));
}
__device__ __forceinline__ v4f mfma16h(v8h a, v8h b, v4f c) {
    return __builtin_amdgcn_mfma_f32_16x16x32_f16(a, b, c, 0, 0, 0);
}
// gfx950 register-file lane swaps (VALU, no LDS/lgkm):
// pswap16(a,b): a-odd-rows <-> b-even-rows  (rows = 16 lanes)
//   a=[a0,b0,a2,b2], b=[a1,b1,a3,b3]
// pswap32(a,b): a-hi-half <-> b-lo-half
//   a=[a01,b01], b=[a23,b23]
__device__ __forceinline__ void pswap16(int &a, int &b) {
    asm("v_permlane16_swap_b32 %0, %1" : "+v"(a), "+v"(b));
}
__device__ __forceinline__ void pswap32(int &a, int &b) {
    asm("v_permlane32_swap_b32 %0, %1" : "+v"(a), "+v"(b));
}
// LDS-only barrier: drain DS, keep global x loads in flight (no vmcnt drain)
__device__ __forceinline__ void barrier_lds() {
    asm volatile("s_waitcnt lgkmcnt(0)" ::: "memory");
    __builtin_amdgcn_s_barrier();
    asm volatile("" ::: "memory");
}

__global__ __launch_bounds__(256)
__attribute__((amdgpu_waves_per_eu(1, 1)))
void gru_pl2(
    const float* __restrict__ x_in,
    const float* __restrict__ Wih0, const float* __restrict__ Whh0,
    const float* __restrict__ bih0, const float* __restrict__ bhh0,
    const float* __restrict__ Wih1, const float* __restrict__ Whh1,
    const float* __restrict__ bih1, const float* __restrict__ bhh1,
    const float* __restrict__ Wih2, const float* __restrict__ Whh2,
    const float* __restrict__ bih2, const float* __restrict__ bhh2,
    const float* __restrict__ Wih3, const float* __restrict__ Whh3,
    const float* __restrict__ bih3, const float* __restrict__ bhh3,
    const float* __restrict__ fcw,  const float* __restrict__ fcb,
    float* __restrict__ out)
{
    // cross-LAYER handoff only (self-h stays in registers + permlane):
    __shared__ int   hbuf[L_ - 1][2][SPI][NB * LDW];
    __shared__ float fchid[NB][L_ * H_];

    const int tid  = threadIdx.x;
    const int w    = tid >> 6;               // wave index == layer index
    const int lane = tid & 63;
    const int q    = lane >> 4;              // k/row-group selector
    const int mm   = lane & 15;              // B-col = batch; A-row = gate n
    const int b0   = blockIdx.x * NB;

    const float *wi, *wh, *bip, *bhp;
    if      (w == 0) { wi = Wih0; wh = Whh0; bip = bih0; bhp = bhh0; }
    else if (w == 1) { wi = Wih1; wh = Whh1; bip = bih1; bhp = bhh1; }
    else if (w == 2) { wi = Wih2; wh = Whh2; bip = bih2; bhp = bhh2; }
    else             { wi = Wih3; wh = Whh3; bip = bih3; bhp = bhh3; }
    const int KX = (w == 0) ? IN_ : H_;

    for (int i = tid; i < (L_ - 1) * 2 * SPI * NB * LDW; i += 256)
        (&hbuf[0][0][0][0])[i] = 0;

    // ---- STATIC A fragments (weights), PRE-SCALED for raw exp2 tail:
    // r,z tiles by -log2e; n_x,n_h tiles (and biases) by -2log2e.
    // tiles: 0=r,1=z,2=n_x,3=n_h; K=32: k<16 x-side, k>=16 h-side.
    const float SC_RZ = -1.4426950408889634f;
    const float SC_N  = -2.8853900817779268f;
    Frag Af[4];
    v4f  cb[4];      // scaled bias as MFMA C; per-lane per-reg: n = q*4+reg
#pragma unroll
    for (int tile = 0; tile < 4; ++tile) {
        const float sc = (tile < 2) ? SC_RZ : SC_N;
        const int rowbase = (tile == 0) ? 0 : (tile == 1) ? 16 : 32;
        const int r = rowbase + mm;
        float vals[8];
#pragma unroll
        for (int e = 0; e < 8; ++e) {
            const int k = q * 8 + e;
            float v = 0.0f;
            if (k < 16) { if (tile != 3 && k < KX) v = wi[r * KX + k]; }
            else        { if (tile != 2)           v = wh[r * H_ + (k - 16)]; }
            vals[e] = v * sc;
        }
#pragma unroll
        for (int d = 0; d < 4; ++d)
            Af[tile].i[d] = pk(vals[2 * d], vals[2 * d + 1]);
#pragma unroll
        for (int reg = 0; reg < 4; ++reg) {
            const int n = q * 4 + reg;
            float b;
            if      (tile == 0) b = bip[n] + bhp[n];
            else if (tile == 1) b = bip[16 + n] + bhp[16 + n];
            else if (tile == 2) b = bip[32 + n];
            else                b = bhp[32 + n];
            cb[tile][reg] = b * sc;
        }
    }
    __syncthreads();

    // ---- x: wave0/q==0 lane mm owns batch b0+mm; f4 loads, double-buffered ----
    const float* xptr = x_in + (size_t)(b0 + mm) * T_ * IN_;
    float XA[5 * SPI], XB[5 * SPI];
#pragma unroll
    for (int c = 0; c < 5 * SPI; ++c) { XA[c] = 0.0f; XB[c] = 0.0f; }
    if (w == 0 && q == 0) {
#pragma unroll
        for (int c = 0; c < 10; ++c)
            ((f4*)XA)[c] = *(const f4_ma*)(xptr + 4 * c);
    }

    float hold[4] = {0.0f, 0.0f, 0.0f, 0.0f};   // exact fp32 h[batch=mm][j=q*4+reg]
    int pkA = 0, pkB = 0;                        // f16 pairs (j q*4..+1, q*4+2..+3)

    const int NI = T_ / SPI + L_ - 1;            // 131

    auto body = [&](int k, float (&Xc)[5 * SPI], float (&Xn)[5 * SPI]) {
        const int t0 = SPI * (k - w);
        if (0 <= t0 && t0 < T_) {
            const int rp = (k - 1) & 1, wp = k & 1;

            // upstream fragments for all SPI steps (published before last barrier)
            Frag up[SPI];
            if (w > 0) {
#pragma unroll
                for (int s = 0; s < SPI; ++s)
                    up[s].i = *(const v4i_ma*)&hbuf[w - 1][rp][s][mm * LDW + (q & 1) * 4];
            }
            // prefetch next interval's x (stays in flight across the barrier)
            if (w == 0 && q == 0) {
                int tn0 = t0 + SPI; if (tn0 > T_ - SPI) tn0 = T_ - SPI;
                const float* xp = xptr + tn0 * IN_;
#pragma unroll
                for (int c = 0; c < 10; ++c)
                    ((f4*)Xn)[c] = *(const f4_ma*)(xp + 4 * c);
            }

#pragma unroll
            for (int s = 0; s < SPI; ++s) {
                // ---- self-h exchange: composed permlane swaps.
                // u=v=pk; pswap32 -> u=[r0,r1,r0,r1], v=[r2,r3,r2,r3];
                // pswap16 -> u=[r0,r2,r0,r2], v=[r1,r3,r1,r3].
                // Row2 (q=2) reads {u=r0, v=r1}; row3 reads {u=r2, v=r3} —
                // exactly ints {k16/24..} with NO per-row selects.
                int uA = pkA, vA = pkA; pswap32(uA, vA); pswap16(uA, vA);
                int uB = pkB, vB = pkB; pswap32(uB, vB); pswap16(uB, vB);

                Frag Bf;   // B[k=q*8+e][col=batch mm]
                {
                    int l0, l1, l2, l3;
                    if (w == 0) {
                        l0 = (q == 0) ? pk(Xc[5 * s + 0], Xc[5 * s + 1]) : 0;
                        l1 = (q == 0) ? pk(Xc[5 * s + 2], Xc[5 * s + 3]) : 0;
                        l2 = (q == 0) ? pk(Xc[5 * s + 4], 0.0f)          : 0;
                        l3 = 0;
                    } else {
                        l0 = up[s].i[0]; l1 = up[s].i[1];
                        l2 = up[s].i[2]; l3 = up[s].i[3];
                    }
                    const bool hi = (q >= 2);
                    Bf.i[0] = hi ? uA : l0;
                    Bf.i[1] = hi ? uB : l1;
                    Bf.i[2] = hi ? vA : l2;
                    Bf.i[3] = hi ? vB : l3;
                }

                // ---- 4 MFMAs: G^T[n][batch], A static, scaled bias in C ----
                v4f a0 = mfma16h(Af[0].h, Bf.h, cb[0]);
                v4f a1 = mfma16h(Af[1].h, Bf.h, cb[1]);
                v4f a2 = mfma16h(Af[2].h, Bf.h, cb[2]);
                v4f a3 = mfma16h(Af[3].h, Bf.h, cb[3]);

                // ---- tail (pre-scaled): r=rcp(1+2^a0), z likewise,
                //      e=2^(a2 + r*a3), n=(1-e)*rcp(1+e), h=n+z*(hold-n) ----
#pragma unroll
                for (int reg = 0; reg < 4; ++reg) {
                    float r = fast_rcp(1.0f + ex2(a0[reg]));
                    float z = fast_rcp(1.0f + ex2(a1[reg]));
                    float e = ex2(fmaf(r, a3[reg], a2[reg]));
                    float n = (1.0f - e) * fast_rcp(1.0f + e);
                    hold[reg] = fmaf(z, hold[reg] - n, n);
                }
                pkA = pk(hold[0], hold[1]);
                pkB = pk(hold[2], hold[3]);

                // ---- downstream handoff (layers 0..2): one b64 write ----
                if (w < 3)
                    *(v2i_ma*)&hbuf[w][wp][s][mm * LDW + q * 2] = (v2i){pkA, pkB};
            }
        }
        barrier_lds();
    };

#pragma unroll 1
    for (int k = 0; k + 1 < NI; k += 2) {
        body(k, XA, XB);
        body(k + 1, XB, XA);
    }
    body(NI - 1, XA, XB);   // k = 130 (even)

    // ---- FC epilogue: exact fp32 hidden from hold regs ----
#pragma unroll
    for (int reg = 0; reg < 4; ++reg)
        fchid[mm][w * H_ + q * 4 + reg] = hold[reg];
    barrier_lds();

    for (int o = tid; o < NB * OUT_; o += 256) {
        const int m = o / OUT_, oc = o % OUT_;
        float acc = fcb[oc];
#pragma unroll
        for (int kk = 0; kk < L_ * H_; ++kk)
            acc = fmaf(fcw[oc * (L_ * H_) + kk], fchid[m][kk], acc);
        out[(size_t)(b0 + m) * OUT_ + oc] = acc;
    }
}

extern "C" void kernel_launch(void* const* d_in, const int* in_sizes, int n_in,
                              void* d_out, int out_size, void* d_ws, size_t ws_size,
                              hipStream_t stream) {
    const float* xin = (const float*)d_in[0];
    // d_in[1] = target_seq: unused by the reference output
    gru_pl2<<<B_ / NB, 256, 0, stream>>>(
        xin,
        (const float*)d_in[2],  (const float*)d_in[3],  (const float*)d_in[4],  (const float*)d_in[5],
        (const float*)d_in[6],  (const float*)d_in[7],  (const float*)d_in[8],  (const float*)d_in[9],
        (const float*)d_in[10], (const float*)d_in[11], (const float*)d_in[12], (const float*)d_in[13],
        (const float*)d_in[14], (const float*)d_in[15], (const float*)d_in[16], (const float*)d_in[17],
        (const float*)d_in[18], (const float*)d_in[19],
        (float*)d_out);
}

// Round 15
// 328.848 us; speedup vs baseline: 2.2527x; 1.0735x over previous
//
#include <hip/hip_runtime.h>

#define B_   4096
#define T_   1024
#define IN_  5
#define H_   16
#define L_   4
#define OUT_ 150
#define NB   16     // batches per block (= MFMA N)
#define LDW  12     // ints per batch-row in LDS (8 used + 4 pad; 48B stride)
#define SPI  16     // GRU steps per barrier interval

typedef int      v4i  __attribute__((ext_vector_type(4)));
typedef int      v2i  __attribute__((ext_vector_type(2)));
typedef float    v4f  __attribute__((ext_vector_type(4)));
typedef float    f4   __attribute__((ext_vector_type(4)));
typedef _Float16 v8h  __attribute__((ext_vector_type(8)));

typedef v4i v4i_ma __attribute__((may_alias));
typedef v2i v2i_ma __attribute__((may_alias));
typedef f4  f4_ma  __attribute__((may_alias));

union Frag { v4i i; v8h h; };

__device__ __forceinline__ float fast_rcp(float x) { return __builtin_amdgcn_rcpf(x); }
__device__ __forceinline__ float ex2(float x) {
#if __has_builtin(__builtin_amdgcn_exp2f)
    return __builtin_amdgcn_exp2f(x);
#else
    return exp2f(x);
#endif
}
__device__ __forceinline__ int pk(float a, float b) {
    return __builtin_bit_cast(int, __builtin_amdgcn_cvt_pkrtz(a, b));
}
__device__ __forceinline__ v4f mfma16h(v8h a, v8h b, v4f c) {
    return __builtin_amdgcn_mfma_f32_16x16x32_f16(a, b, c, 0, 0, 0);
}
// gfx950 register-file lane swaps (VALU, no LDS/lgkm). Composition (R14-verified):
// u=v=x; pswap32(u,v); pswap16(u,v) => u=[r0,r2,r0,r2], v=[r1,r3,r1,r3]
// so row2 reads {u=r0, v=r1}, row3 reads {u=r2, v=r3} with zero selects.
__device__ __forceinline__ void pswap16(int &a, int &b) {
    asm("v_permlane16_swap_b32 %0, %1" : "+v"(a), "+v"(b));
}
__device__ __forceinline__ void pswap32(int &a, int &b) {
    asm("v_permlane32_swap_b32 %0, %1" : "+v"(a), "+v"(b));
}
// LDS-only barrier: drain DS, keep global x loads in flight (no vmcnt drain)
__device__ __forceinline__ void barrier_lds() {
    asm volatile("s_waitcnt lgkmcnt(0)" ::: "memory");
    __builtin_amdgcn_s_barrier();
    asm volatile("" ::: "memory");
}

__global__ __launch_bounds__(256)
__attribute__((amdgpu_waves_per_eu(1, 1)))
void gru_pl3(
    const float* __restrict__ x_in,
    const float* __restrict__ Wih0, const float* __restrict__ Whh0,
    const float* __restrict__ bih0, const float* __restrict__ bhh0,
    const float* __restrict__ Wih1, const float* __restrict__ Whh1,
    const float* __restrict__ bih1, const float* __restrict__ bhh1,
    const float* __restrict__ Wih2, const float* __restrict__ Whh2,
    const float* __restrict__ bih2, const float* __restrict__ bhh2,
    const float* __restrict__ Wih3, const float* __restrict__ Whh3,
    const float* __restrict__ bih3, const float* __restrict__ bhh3,
    const float* __restrict__ fcw,  const float* __restrict__ fcb,
    float* __restrict__ out)
{
    // cross-LAYER handoff only (self-h stays in registers + permlane):
    __shared__ int   hbuf[L_ - 1][2][SPI][NB * LDW];
    __shared__ float fchid[NB][L_ * H_];

    const int tid  = threadIdx.x;
    const int w    = tid >> 6;               // wave index == layer index
    const int lane = tid & 63;
    const int q    = lane >> 4;              // k/row-group selector
    const int mm   = lane & 15;              // B-col = batch; A-row = gate n
    const int b0   = blockIdx.x * NB;

    const float *wi, *wh, *bip, *bhp;
    if      (w == 0) { wi = Wih0; wh = Whh0; bip = bih0; bhp = bhh0; }
    else if (w == 1) { wi = Wih1; wh = Whh1; bip = bih1; bhp = bhh1; }
    else if (w == 2) { wi = Wih2; wh = Whh2; bip = bih2; bhp = bhh2; }
    else             { wi = Wih3; wh = Whh3; bip = bih3; bhp = bhh3; }
    const int KX = (w == 0) ? IN_ : H_;

    for (int i = tid; i < (L_ - 1) * 2 * SPI * NB * LDW; i += 256)
        (&hbuf[0][0][0][0])[i] = 0;

    // ---- STATIC A fragments (weights), PRE-SCALED for raw exp2 tail:
    // r,z tiles by -log2e; n_x,n_h tiles (and biases) by -2log2e.
    // tiles: 0=r,1=z,2=n_x,3=n_h; K=32: k<16 x-side, k>=16 h-side.
    const float SC_RZ = -1.4426950408889634f;
    const float SC_N  = -2.8853900817779268f;
    Frag Af[4];
    v4f  cb[4];      // scaled bias as MFMA C; per-lane per-reg: n = q*4+reg
#pragma unroll
    for (int tile = 0; tile < 4; ++tile) {
        const float sc = (tile < 2) ? SC_RZ : SC_N;
        const int rowbase = (tile == 0) ? 0 : (tile == 1) ? 16 : 32;
        const int r = rowbase + mm;
        float vals[8];
#pragma unroll
        for (int e = 0; e < 8; ++e) {
            const int k = q * 8 + e;
            float v = 0.0f;
            if (k < 16) { if (tile != 3 && k < KX) v = wi[r * KX + k]; }
            else        { if (tile != 2)           v = wh[r * H_ + (k - 16)]; }
            vals[e] = v * sc;
        }
#pragma unroll
        for (int d = 0; d < 4; ++d)
            Af[tile].i[d] = pk(vals[2 * d], vals[2 * d + 1]);
#pragma unroll
        for (int reg = 0; reg < 4; ++reg) {
            const int n = q * 4 + reg;
            float b;
            if      (tile == 0) b = bip[n] + bhp[n];
            else if (tile == 1) b = bip[16 + n] + bhp[16 + n];
            else if (tile == 2) b = bip[32 + n];
            else                b = bhp[32 + n];
            cb[tile][reg] = b * sc;
        }
    }
    __syncthreads();

    // ---- x: wave0/q==0 lane mm owns batch b0+mm; f4 loads, double-buffered ----
    const float* xptr = x_in + (size_t)(b0 + mm) * T_ * IN_;
    float XA[5 * SPI], XB[5 * SPI];
#pragma unroll
    for (int c = 0; c < 5 * SPI; ++c) { XA[c] = 0.0f; XB[c] = 0.0f; }
    if (w == 0 && q == 0) {
#pragma unroll
        for (int c = 0; c < (5 * SPI) / 4; ++c)
            ((f4*)XA)[c] = *(const f4_ma*)(xptr + 4 * c);
    }

    float hold[4] = {0.0f, 0.0f, 0.0f, 0.0f};   // exact fp32 h[batch=mm][j=q*4+reg]
    int pkA = 0, pkB = 0;                        // f16 pairs (j q*4..+1, q*4+2..+3)

    const int NI = T_ / SPI + L_ - 1;            // 67

    auto body = [&](int k, float (&Xc)[5 * SPI], float (&Xn)[5 * SPI]) {
        const int t0 = SPI * (k - w);
        if (0 <= t0 && t0 < T_) {
            const int rp = (k - 1) & 1, wp = k & 1;

            // upstream fragments for all SPI steps (published before last barrier)
            Frag up[SPI];
            if (w > 0) {
#pragma unroll
                for (int s = 0; s < SPI; ++s)
                    up[s].i = *(const v4i_ma*)&hbuf[w - 1][rp][s][mm * LDW + (q & 1) * 4];
            }
            // prefetch next interval's x (stays in flight across the barrier)
            if (w == 0 && q == 0) {
                int tn0 = t0 + SPI; if (tn0 > T_ - SPI) tn0 = T_ - SPI;
                const float* xp = xptr + tn0 * IN_;
#pragma unroll
                for (int c = 0; c < (5 * SPI) / 4; ++c)
                    ((f4*)Xn)[c] = *(const f4_ma*)(xp + 4 * c);
            }

#pragma unroll
            for (int s = 0; s < SPI; ++s) {
                // ---- self-h exchange: composed permlane swaps (R14-verified) ----
                int uA = pkA, vA = pkA; pswap32(uA, vA); pswap16(uA, vA);
                int uB = pkB, vB = pkB; pswap32(uB, vB); pswap16(uB, vB);

                Frag Bf;   // B[k=q*8+e][col=batch mm]
                {
                    int l0, l1, l2, l3;
                    if (w == 0) {
                        l0 = (q == 0) ? pk(Xc[5 * s + 0], Xc[5 * s + 1]) : 0;
                        l1 = (q == 0) ? pk(Xc[5 * s + 2], Xc[5 * s + 3]) : 0;
                        l2 = (q == 0) ? pk(Xc[5 * s + 4], 0.0f)          : 0;
                        l3 = 0;
                    } else {
                        l0 = up[s].i[0]; l1 = up[s].i[1];
                        l2 = up[s].i[2]; l3 = up[s].i[3];
                    }
                    const bool hi = (q >= 2);
                    Bf.i[0] = hi ? uA : l0;
                    Bf.i[1] = hi ? uB : l1;
                    Bf.i[2] = hi ? vA : l2;
                    Bf.i[3] = hi ? vB : l3;
                }

                // ---- 4 MFMAs: G^T[n][batch], A static, scaled bias in C ----
                v4f a0 = mfma16h(Af[0].h, Bf.h, cb[0]);
                v4f a1 = mfma16h(Af[1].h, Bf.h, cb[1]);
                v4f a2 = mfma16h(Af[2].h, Bf.h, cb[2]);
                v4f a3 = mfma16h(Af[3].h, Bf.h, cb[3]);

                // ---- tail (pre-scaled, rational blend — 3 ex2 + 2 rcp):
                // e_r=2^a0; r=1/(1+e_r); f=2^(a2+r*a3); e_z=2^a1;
                // h = [hold(1+f) + e_z(1-f)] / [(1+e_z)(1+f)]
#pragma unroll
                for (int reg = 0; reg < 4; ++reg) {
                    float er = ex2(a0[reg]);
                    float r  = fast_rcp(1.0f + er);
                    float f  = ex2(fmaf(r, a3[reg], a2[reg]));
                    float ez = ex2(a1[reg]);
                    float num = fmaf(hold[reg], f, hold[reg]) + fmaf(-ez, f, ez);
                    float d1  = 1.0f + ez;
                    float den = fmaf(d1, f, d1);
                    hold[reg] = num * fast_rcp(den);
                }
                pkA = pk(hold[0], hold[1]);
                pkB = pk(hold[2], hold[3]);

                // ---- downstream handoff (layers 0..2): one b64 write ----
                if (w < 3)
                    *(v2i_ma*)&hbuf[w][wp][s][mm * LDW + q * 2] = (v2i){pkA, pkB};
            }
        }
        barrier_lds();
    };

#pragma unroll 1
    for (int k = 0; k + 1 < NI; k += 2) {
        body(k, XA, XB);
        body(k + 1, XB, XA);
    }
    body(NI - 1, XA, XB);   // k = 66 (even)

    // ---- FC epilogue: exact fp32 hidden from hold regs ----
#pragma unroll
    for (int reg = 0; reg < 4; ++reg)
        fchid[mm][w * H_ + q * 4 + reg] = hold[reg];
    barrier_lds();

    for (int o = tid; o < NB * OUT_; o += 256) {
        const int m = o / OUT_, oc = o % OUT_;
        float acc = fcb[oc];
#pragma unroll
        for (int kk = 0; kk < L_ * H_; ++kk)
            acc = fmaf(fcw[oc * (L_ * H_) + kk], fchid[m][kk], acc);
        out[(size_t)(b0 + m) * OUT_ + oc] = acc;
    }
}

extern "C" void kernel_launch(void* const* d_in, const int* in_sizes, int n_in,
                              void* d_out, int out_size, void* d_ws, size_t ws_size,
                              hipStream_t stream) {
    const float* xin = (const float*)d_in[0];
    // d_in[1] = target_seq: unused by the reference output
    gru_pl3<<<B_ / NB, 256, 0, stream>>>(
        xin,
        (const float*)d_in[2],  (const float*)d_in[3],  (const float*)d_in[4],  (const float*)d_in[5],
        (const float*)d_in[6],  (const float*)d_in[7],  (const float*)d_in[8],  (const float*)d_in[9],
        (const float*)d_in[10], (const float*)d_in[11], (const float*)d_in[12], (const float*)d_in[13],
        (const float*)d_in[14], (const float*)d_in[15], (const float*)d_in[16], (const float*)d_in[17],
        (const float*)d_in[18], (const float*)d_in[19],
        (float*)d_out);
}